// Round 13
// baseline (422.632 us; speedup 1.0000x reference)
//
#include <hip/hip_runtime.h>
#include <math.h>

#define B_Q   128
#define DIM   512
#define NCORP 500000
#define NTILES 31250           // 16-row tiles (exact)
#define G_SCAN 512             // 2 blocks/CU

typedef short short8 __attribute__((ext_vector_type(8)));
typedef float floatx4 __attribute__((ext_vector_type(4)));

__device__ __forceinline__ unsigned short bf16_rne(float x) {
    unsigned u = __float_as_uint(x);
    return (unsigned short)((u + 0x7FFFu + ((u >> 16) & 1u)) >> 16);
}

// pack two f32 -> two bf16 (truncation) in one v_perm (verified r6-r12)
__device__ __forceinline__ unsigned pack2(float hi, float lo) {
    return __builtin_amdgcn_perm(__float_as_uint(hi), __float_as_uint(lo),
                                 0x07060302u);
}

__device__ __forceinline__ void ins3(float s, int id,
                                     float& b0, float& b1, float& b2,
                                     int& i0, int& i1, int& i2) {
    if (s > b0)      { b2 = b1; i2 = i1; b1 = b0; i1 = i0; b0 = s; i0 = id; }
    else if (s > b1) { b2 = b1; i2 = i1; b1 = s;  i1 = id; }
    else if (s > b2) { b2 = s;  i2 = id; }
}

__device__ __forceinline__ void ins2(float s, int id,
                                     float& b0, float& b1, int& i0, int& i1) {
    if (s > b0)      { b1 = b0; i1 = i0; b0 = s; i0 = id; }
    else if (s > b1) { b1 = s;  i1 = id; }
}

__device__ __forceinline__ void ins8(float s, int id, float* bs, int* bi) {
#pragma unroll
    for (int j = 0; j < 8; ++j) {
        if (s > bs[j]) {
            float tf = bs[j]; int tx = bi[j];
            bs[j] = s; bi[j] = id; s = tf; id = tx;
        }
    }
}

// ---------------------------------------------------------------------------
// Kernel A: query = query_r @ W ; L2-normalize ; write
//  (a) exact qn f32 row-major (for rescore)
//  (b) bf16 MFMA B-fragment-linear: idx = kc*4096 + qg*512 + (g*16+q15)*8 + e
// ---------------------------------------------------------------------------
__global__ void proj_kernel(const float* __restrict__ qr,
                            const float* __restrict__ W,
                            float* __restrict__ qn,
                            unsigned short* __restrict__ qfrag) {
    __shared__ float qrow[DIM];
    __shared__ float red[256];
    const int b = blockIdx.x;
    const int t = threadIdx.x;

    qrow[t]       = qr[b * DIM + t];
    qrow[t + 256] = qr[b * DIM + t + 256];
    __syncthreads();

    float acc0 = 0.f, acc1 = 0.f;
#pragma unroll 8
    for (int k = 0; k < DIM; ++k) {
        const float q = qrow[k];
        acc0 = fmaf(q, W[k * DIM + t],       acc0);
        acc1 = fmaf(q, W[k * DIM + t + 256], acc1);
    }

    red[t] = acc0 * acc0 + acc1 * acc1;
    __syncthreads();
    for (int s = 128; s > 0; s >>= 1) {
        if (t < s) red[t] += red[t + s];
        __syncthreads();
    }
    const float inv = 1.0f / fmaxf(sqrtf(red[0]), 1e-6f);

    const int qg = b >> 4, q15 = b & 15;
#pragma unroll
    for (int half = 0; half < 2; ++half) {
        const int d = t + half * 256;
        const float x = (half == 0 ? acc0 : acc1) * inv;
        qn[b * DIM + d] = x;
        const int kc = d >> 5, kk = d & 31, g = kk >> 3, e = kk & 7;
        qfrag[(size_t)kc * 4096 + qg * 512 + (g * 16 + q15) * 8 + e] = bf16_rne(x);
    }
}

// ---------------------------------------------------------------------------
// Kernel B: MFMA cosine scan, 2 blocks/CU, depth-2 tile prefetch.
//  - Wave w holds its query group's fragments in REGISTERS (64 VGPR).
//  - LDS/block = 32 KB: double-buffered 16-row bf16 A-tile (R11 swizzle).
//  - Contiguous ~61-tile segment per block; coalesced cooperative staging.
//  - Two reg sets rA/rB: BODY(T, rA) consumes loads issued 2 bodies ago.
//  - 1 lgkmcnt+s_barrier per tile; vmcnt never drained to 0.
//  - Row norms via mfma(a,a) diagonal (verified r10-r12).
// ---------------------------------------------------------------------------
__global__ __launch_bounds__(512, 4) void scan_kernel(
        const float* __restrict__ corpus,
        const unsigned short* __restrict__ qfrag,
        float* __restrict__ cand_s,
        int*   __restrict__ cand_i) {
    __shared__ __align__(16) unsigned char smem[32768];   // 2 x 16 KB A-tiles

    const int t = threadIdx.x;
    const int w = t >> 6, l = t & 63;
    const int h = l >> 4, q15 = l & 15;

    // ---- Q fragments for this wave's query group -> registers ----
    short8 qreg[16];
#pragma unroll
    for (int kc = 0; kc < 16; ++kc)
        qreg[kc] = *(const short8*)(qfrag + (size_t)kc * 4096 + w * 512 + l * 8);

    // ---- staging constants (R11/R12-verified): LDS byte offsets only ----
    int lby[4];
#pragma unroll
    for (int p = 0; p < 4; ++p) {
        const int i4 = p * 512 + t;          // flat float4 idx in 32 KB tile
        const int r  = i4 >> 7;              // row 0..15
        const int c4 = i4 & 127;             // float4 within row
        const int kc = c4 >> 3, g = (c4 >> 1) & 3, e0 = (c4 & 1) * 4;
        lby[p]  = kc * 1024 + (((g * 16 + r) ^ (kc & 7)) << 4) + e0 * 2;
    }

    // ---- contiguous segment: 512 blocks x 61-62 tiles = 31250 ----
    const int b = blockIdx.x;
    const int tstart = b * 61 + (b < 18 ? b : 18);
    const int tcount = 61 + (b < 18 ? 1 : 0);
    const float* seg = corpus + (size_t)tstart * 8192 + t * 4;  // + p*2048

    float ts0 = -1e30f, ts1 = -1e30f;
    int   ti0 = 0, ti1 = 0;

    float4 rA[4], rB[4];
#pragma unroll
    for (int p = 0; p < 4; ++p) rA[p] = *(const float4*)(seg + p * 2048);
#pragma unroll
    for (int p = 0; p < 4; ++p) rB[p] = *(const float4*)(seg + 8192 + p * 2048);

    auto BODY = [&](int T, float4* rr, unsigned char* bb) {
        // write tile T (in rr, loaded 2 bodies ago) to LDS frag buffer
#pragma unroll
        for (int p = 0; p < 4; ++p) {
            uint2 d;
            d.x = pack2(rr[p].y, rr[p].x);
            d.y = pack2(rr[p].w, rr[p].z);
            *(uint2*)(bb + lby[p]) = d;
        }
        // prefetch tile T+2 (sequential) into the same reg set (WAR-safe)
        {
            const int Tn = (T + 2 < tcount) ? T + 2 : T;
            const float* src = seg + (size_t)Tn * 8192;
#pragma unroll
            for (int p = 0; p < 4; ++p) rr[p] = *(const float4*)(src + p * 2048);
        }
        __builtin_amdgcn_sched_barrier(0);
        asm volatile("s_waitcnt lgkmcnt(0)" ::: "memory");
        __builtin_amdgcn_s_barrier();
        __builtin_amdgcn_sched_barrier(0);

        // compute: 16 kc x { swizzled A read, norm MFMA, score MFMA }
        floatx4 acc  = {0.f, 0.f, 0.f, 0.f};
        floatx4 accN = {0.f, 0.f, 0.f, 0.f};
#pragma unroll
        for (int kc = 0; kc < 16; ++kc) {
            const short8 a = *(const short8*)(bb + kc * 1024 +
                                              ((l ^ (kc & 7)) << 4));
            accN = __builtin_amdgcn_mfma_f32_16x16x32_bf16(a, a, accN, 0, 0, 0);
            acc  = __builtin_amdgcn_mfma_f32_16x16x32_bf16(a, qreg[kc], acc, 0, 0, 0);
        }

        // epilogue: row m = h*4+reg; norm diag at lane h*20+reg (r10-r12)
        const int grow = (tstart + T) * 16;
#pragma unroll
        for (int reg = 0; reg < 4; ++reg) {
            const float nrm = __shfl(accN[reg], h * 20 + reg, 64);
            const float inv = 1.0f / fmaxf(sqrtf(nrm), 1e-6f);
            ins2(acc[reg] * inv, grow + h * 4 + reg, ts0, ts1, ti0, ti1);
        }
    };

#pragma unroll 1
    for (int T = 0; T + 1 < tcount; T += 2) {
        BODY(T,     rA, smem);
        BODY(T + 1, rB, smem + 16384);
    }
    if (tcount & 1) BODY(tcount - 1, rA, smem);

    // ---- block merge: per query 4 h-slots x top2 -> per-block top-3 ----
    __syncthreads();
    float* msc = (float*)smem;                 // [128][4][2] = 4 KB
    int*   mid = (int*)(smem + 4096);          // 4 KB
    {
        const int myq = w * 16 + q15;
        msc[(myq * 4 + h) * 2 + 0] = ts0;  mid[(myq * 4 + h) * 2 + 0] = ti0;
        msc[(myq * 4 + h) * 2 + 1] = ts1;  mid[(myq * 4 + h) * 2 + 1] = ti1;
    }
    __syncthreads();
    if (t < B_Q) {
        float b0 = -1e30f, b1 = -1e30f, b2 = -1e30f;
        int   i0 = 0, i1 = 0, i2 = 0;
        for (int e = 0; e < 8; ++e)
            ins3(msc[t * 8 + e], mid[t * 8 + e], b0, b1, b2, i0, i1, i2);
        const size_t base = ((size_t)blockIdx.x * B_Q + t) * 3;
        cand_s[base + 0] = b0; cand_s[base + 1] = b1; cand_s[base + 2] = b2;
        cand_i[base + 0] = i0; cand_i[base + 1] = i1; cand_i[base + 2] = i2;
    }
}

// ---------------------------------------------------------------------------
// Kernel C: merge per-block candidates -> global approx top-8 per query.
// ---------------------------------------------------------------------------
__global__ void merge_topk_kernel(const float* __restrict__ cand_s,
                                  const int*   __restrict__ cand_i,
                                  int nblk,
                                  float* __restrict__ topT_s,
                                  int*   __restrict__ topT_i) {
    __shared__ float ls[256 * 8];
    __shared__ int   li[256 * 8];
    const int q = blockIdx.x;
    const int t = threadIdx.x;

    float bs[8]; int bi[8];
#pragma unroll
    for (int j = 0; j < 8; ++j) { bs[j] = -1e30f; bi[j] = -1; }

    for (int blk = t; blk < nblk; blk += 256) {
        const size_t base = ((size_t)blk * B_Q + q) * 3;
#pragma unroll
        for (int j = 0; j < 3; ++j)
            ins8(cand_s[base + j], cand_i[base + j], bs, bi);
    }
#pragma unroll
    for (int j = 0; j < 8; ++j) { ls[t * 8 + j] = bs[j]; li[t * 8 + j] = bi[j]; }
    __syncthreads();

    for (int s = 128; s > 0; s >>= 1) {
        if (t < s) {
#pragma unroll
            for (int j = 0; j < 8; ++j)
                ins8(ls[(t + s) * 8 + j], li[(t + s) * 8 + j], bs, bi);
#pragma unroll
            for (int j = 0; j < 8; ++j) { ls[t * 8 + j] = bs[j]; li[t * 8 + j] = bi[j]; }
        }
        __syncthreads();
    }
    if (t == 0) {
#pragma unroll
        for (int j = 0; j < 8; ++j) { topT_s[q * 8 + j] = bs[j]; topT_i[q * 8 + j] = bi[j]; }
    }
}

// ---------------------------------------------------------------------------
// Kernel D: exact f32 rescore of 8 candidates per query -> top-3 -> out.
// d_out: [0..383] scores f32, [384..767] indices stored as f32 values.
// ---------------------------------------------------------------------------
__global__ void rescore_kernel(const float* __restrict__ corpus,
                               const float* __restrict__ qn,
                               const int*   __restrict__ topT_i,
                               float* __restrict__ out) {
    __shared__ float qrow[DIM];
    __shared__ float sc[8];
    const int q = blockIdx.x;
    const int t = threadIdx.x;
    const int g = t >> 5;       // candidate 0..7
    const int lane = t & 31;

    qrow[t]       = qn[q * DIM + t];
    qrow[t + 256] = qn[q * DIM + t + 256];
    __syncthreads();

    const int r = topT_i[q * 8 + g];
    float d = 0.f, n = 0.f;
    if (r >= 0) {
        const float* row = corpus + (size_t)r * DIM;
        for (int j = lane; j < DIM; j += 32) {
            const float c = row[j];
            d = fmaf(qrow[j], c, d);
            n = fmaf(c, c, n);
        }
    }
#pragma unroll
    for (int m = 16; m > 0; m >>= 1) {
        d += __shfl_xor(d, m);
        n += __shfl_xor(n, m);
    }
    if (lane == 0)
        sc[g] = (r >= 0) ? d / fmaxf(sqrtf(n), 1e-6f) : -1e30f;
    __syncthreads();

    if (t == 0) {
        float b0 = -1e30f, b1 = -1e30f, b2 = -1e30f;
        int   i0 = 0, i1 = 0, i2 = 0;
#pragma unroll
        for (int e = 0; e < 8; ++e)
            ins3(sc[e], topT_i[q * 8 + e], b0, b1, b2, i0, i1, i2);
        out[q * 3 + 0] = b0;
        out[q * 3 + 1] = b1;
        out[q * 3 + 2] = b2;
        out[B_Q * 3 + q * 3 + 0] = (float)i0;
        out[B_Q * 3 + q * 3 + 1] = (float)i1;
        out[B_Q * 3 + q * 3 + 2] = (float)i2;
    }
}

// ---------------------------------------------------------------------------
extern "C" void kernel_launch(void* const* d_in, const int* in_sizes, int n_in,
                              void* d_out, int out_size, void* d_ws, size_t ws_size,
                              hipStream_t stream) {
    const float* qr     = (const float*)d_in[0];  // [128,512]
    const float* corpus = (const float*)d_in[1];  // [500000,512]
    const float* W      = (const float*)d_in[2];  // [512,512]

    float* out = (float*)d_out;
    char*  ws  = (char*)d_ws;

    float*          qn     = (float*)ws;                      // 256 KB
    unsigned short* qfrag  = (unsigned short*)(ws + 262144);  // 128 KB
    float*          topT_s = (float*)(ws + 393216);           // 4 KB
    int*            topT_i = (int*)(ws + 397312);             // 4 KB
    const size_t head = 401408;

    float* cand_s = (float*)(ws + head);                      // 512*128*3 f32
    int*   cand_i = (int*)(ws + head + (size_t)G_SCAN * B_Q * 3 * sizeof(float));

    proj_kernel<<<B_Q, 256, 0, stream>>>(qr, W, qn, qfrag);
    scan_kernel<<<G_SCAN, 512, 0, stream>>>(corpus, qfrag, cand_s, cand_i);
    merge_topk_kernel<<<B_Q, 256, 0, stream>>>(cand_s, cand_i, G_SCAN, topT_s, topT_i);
    rescore_kernel<<<B_Q, 256, 0, stream>>>(corpus, qn, topT_i, out);
}

// Round 14
// 372.733 us; speedup vs baseline: 1.1339x; 1.1339x over previous
//
#include <hip/hip_runtime.h>
#include <math.h>

#define B_Q   128
#define DIM   512
#define NCORP 500000
#define NTILES 31250           // 16-row tiles (exact)
#define G_SCAN 512             // 2 blocks/CU

typedef short short8 __attribute__((ext_vector_type(8)));
typedef float floatx4 __attribute__((ext_vector_type(4)));

__device__ __forceinline__ unsigned short bf16_rne(float x) {
    unsigned u = __float_as_uint(x);
    return (unsigned short)((u + 0x7FFFu + ((u >> 16) & 1u)) >> 16);
}

// pack two f32 -> two bf16 (truncation) in one v_perm (verified r6-r12)
__device__ __forceinline__ unsigned pack2(float hi, float lo) {
    return __builtin_amdgcn_perm(__float_as_uint(hi), __float_as_uint(lo),
                                 0x07060302u);
}

__device__ __forceinline__ void ins3(float s, int id,
                                     float& b0, float& b1, float& b2,
                                     int& i0, int& i1, int& i2) {
    if (s > b0)      { b2 = b1; i2 = i1; b1 = b0; i1 = i0; b0 = s; i0 = id; }
    else if (s > b1) { b2 = b1; i2 = i1; b1 = s;  i1 = id; }
    else if (s > b2) { b2 = s;  i2 = id; }
}

__device__ __forceinline__ void ins2(float s, int id,
                                     float& b0, float& b1, int& i0, int& i1) {
    if (s > b0)      { b1 = b0; i1 = i0; b0 = s; i0 = id; }
    else if (s > b1) { b1 = s;  i1 = id; }
}

__device__ __forceinline__ void ins8(float s, int id, float* bs, int* bi) {
#pragma unroll
    for (int j = 0; j < 8; ++j) {
        if (s > bs[j]) {
            float tf = bs[j]; int tx = bi[j];
            bs[j] = s; bi[j] = id; s = tf; id = tx;
        }
    }
}

// ---------------------------------------------------------------------------
// Kernel A: query = query_r @ W ; L2-normalize ; write
//  (a) exact qn f32 row-major (for rescore)
//  (b) bf16 MFMA B-fragment-linear: idx = kc*4096 + qg*512 + (g*16+q15)*8 + e
// ---------------------------------------------------------------------------
__global__ void proj_kernel(const float* __restrict__ qr,
                            const float* __restrict__ W,
                            float* __restrict__ qn,
                            unsigned short* __restrict__ qfrag) {
    __shared__ float qrow[DIM];
    __shared__ float red[256];
    const int b = blockIdx.x;
    const int t = threadIdx.x;

    qrow[t]       = qr[b * DIM + t];
    qrow[t + 256] = qr[b * DIM + t + 256];
    __syncthreads();

    float acc0 = 0.f, acc1 = 0.f;
#pragma unroll 8
    for (int k = 0; k < DIM; ++k) {
        const float q = qrow[k];
        acc0 = fmaf(q, W[k * DIM + t],       acc0);
        acc1 = fmaf(q, W[k * DIM + t + 256], acc1);
    }

    red[t] = acc0 * acc0 + acc1 * acc1;
    __syncthreads();
    for (int s = 128; s > 0; s >>= 1) {
        if (t < s) red[t] += red[t + s];
        __syncthreads();
    }
    const float inv = 1.0f / fmaxf(sqrtf(red[0]), 1e-6f);

    const int qg = b >> 4, q15 = b & 15;
#pragma unroll
    for (int half = 0; half < 2; ++half) {
        const int d = t + half * 256;
        const float x = (half == 0 ? acc0 : acc1) * inv;
        qn[b * DIM + d] = x;
        const int kc = d >> 5, kk = d & 31, g = kk >> 3, e = kk & 7;
        qfrag[(size_t)kc * 4096 + qg * 512 + (g * 16 + q15) * 8 + e] = bf16_rne(x);
    }
}

// ---------------------------------------------------------------------------
// Kernel B: MFMA cosine scan, 2 blocks/CU (R12 structure).
//  - Wave w holds its query group's fragments in REGISTERS (64 VGPR).
//  - LDS/block = 32 KB A dbuf + 256 B norm partials (parity dbuf).
//  - Contiguous ~61-tile segment per block; coalesced cooperative staging.
//  - Norms: exact-f32 partials at stage time + wave shfl butterfly ->
//    npart[16][2] in LDS (replaces the 16 redundant mfma(a,a) per wave).
//  - 1 lgkmcnt+s_barrier per tile; vmcnt never drained to 0.
// ---------------------------------------------------------------------------
__global__ __launch_bounds__(512, 4) void scan_kernel(
        const float* __restrict__ corpus,
        const unsigned short* __restrict__ qfrag,
        float* __restrict__ cand_s,
        int*   __restrict__ cand_i) {
    __shared__ __align__(16) unsigned char smem[33024];   // 2x16KB A + 2x128B np

    const int t = threadIdx.x;
    const int w = t >> 6, l = t & 63;
    const int h = l >> 4, q15 = l & 15;

    // ---- Q fragments for this wave's query group -> registers ----
    short8 qreg[16];
#pragma unroll
    for (int kc = 0; kc < 16; ++kc)
        qreg[kc] = *(const short8*)(qfrag + (size_t)kc * 4096 + w * 512 + l * 8);

    // ---- staging constants (R11/R12-verified): LDS byte offsets ----
    int lby[4];
#pragma unroll
    for (int p = 0; p < 4; ++p) {
        const int i4 = p * 512 + t;          // flat float4 idx in 32 KB tile
        const int r  = i4 >> 7;              // row 0..15  (= p*4 + (t>>7))
        const int c4 = i4 & 127;             // float4 within row
        const int kc = c4 >> 3, g = (c4 >> 1) & 3, e0 = (c4 & 1) * 4;
        lby[p]  = kc * 1024 + (((g * 16 + r) ^ (kc & 7)) << 4) + e0 * 2;
    }

    // ---- contiguous segment: 512 blocks x 61-62 tiles = 31250 ----
    const int b = blockIdx.x;
    const int tstart = b * 61 + (b < 18 ? b : 18);
    const int tcount = 61 + (b < 18 ? 1 : 0);
    const float* seg = corpus + (size_t)tstart * 8192 + t * 4;  // + p*2048

    float ts0 = -1e30f, ts1 = -1e30f;
    int   ti0 = 0, ti1 = 0;

    float4 rr[4];
#pragma unroll
    for (int p = 0; p < 4; ++p) rr[p] = *(const float4*)(seg + p * 2048);

#pragma unroll 1
    for (int T = 0; T < tcount; ++T) {
        const int par = T & 1;
        unsigned char* bb = smem + par * 16384;
        float* np = (float*)(smem + 32768 + par * 128);   // [16][2] f32

        // write tile T (in rr) to LDS frag buffer + exact f32 norm partials
        float n[4];
#pragma unroll
        for (int p = 0; p < 4; ++p) {
            float s = rr[p].x * rr[p].x;
            s = fmaf(rr[p].y, rr[p].y, s);
            s = fmaf(rr[p].z, rr[p].z, s);
            s = fmaf(rr[p].w, rr[p].w, s);
            n[p] = s;
            uint2 d;
            d.x = pack2(rr[p].y, rr[p].x);
            d.y = pack2(rr[p].w, rr[p].z);
            *(uint2*)(bb + lby[p]) = d;
        }
        // wave butterfly: sum each piece's partial over the wave's 64 cols
#pragma unroll
        for (int s = 1; s < 64; s <<= 1) {
            n[0] += __shfl_xor(n[0], s);
            n[1] += __shfl_xor(n[1], s);
            n[2] += __shfl_xor(n[2], s);
            n[3] += __shfl_xor(n[3], s);
        }
        if (l == 0) {
            const int rb = w >> 1, ch = w & 1;    // rows p*4+rb, col-half ch
#pragma unroll
            for (int p = 0; p < 4; ++p)
                np[(p * 4 + rb) * 2 + ch] = n[p];
        }
        // prefetch tile T+1 (sequential) into the same regs (WAR-safe)
        {
            const int Tn = (T + 1 < tcount) ? T + 1 : T;
            const float* src = seg + (size_t)Tn * 8192;
#pragma unroll
            for (int p = 0; p < 4; ++p) rr[p] = *(const float4*)(src + p * 2048);
        }
        __builtin_amdgcn_sched_barrier(0);
        asm volatile("s_waitcnt lgkmcnt(0)" ::: "memory");
        __builtin_amdgcn_s_barrier();
        __builtin_amdgcn_sched_barrier(0);

        // compute: 16 kc x { swizzled A read, score MFMA }  (norm MFMAs gone)
        floatx4 acc = {0.f, 0.f, 0.f, 0.f};
#pragma unroll
        for (int kc = 0; kc < 16; ++kc) {
            const short8 a = *(const short8*)(bb + kc * 1024 +
                                              ((l ^ (kc & 7)) << 4));
            acc = __builtin_amdgcn_mfma_f32_16x16x32_bf16(a, qreg[kc], acc, 0, 0, 0);
        }

        // epilogue: row m = h*4+reg; norm from npart (broadcast reads)
        const int grow = (tstart + T) * 16;
#pragma unroll
        for (int reg = 0; reg < 4; ++reg) {
            const int m = h * 4 + reg;
            const float nrm = np[m * 2] + np[m * 2 + 1];
            const float inv = 1.0f / fmaxf(sqrtf(nrm), 1e-6f);
            ins2(acc[reg] * inv, grow + m, ts0, ts1, ti0, ti1);
        }
    }

    // ---- block merge: per query 4 h-slots x top2 -> per-block top-3 ----
    __syncthreads();
    float* msc = (float*)smem;                 // [128][4][2] = 4 KB
    int*   mid = (int*)(smem + 4096);          // 4 KB
    {
        const int myq = w * 16 + q15;
        msc[(myq * 4 + h) * 2 + 0] = ts0;  mid[(myq * 4 + h) * 2 + 0] = ti0;
        msc[(myq * 4 + h) * 2 + 1] = ts1;  mid[(myq * 4 + h) * 2 + 1] = ti1;
    }
    __syncthreads();
    if (t < B_Q) {
        float b0 = -1e30f, b1 = -1e30f, b2 = -1e30f;
        int   i0 = 0, i1 = 0, i2 = 0;
        for (int e = 0; e < 8; ++e)
            ins3(msc[t * 8 + e], mid[t * 8 + e], b0, b1, b2, i0, i1, i2);
        const size_t base = ((size_t)blockIdx.x * B_Q + t) * 3;
        cand_s[base + 0] = b0; cand_s[base + 1] = b1; cand_s[base + 2] = b2;
        cand_i[base + 0] = i0; cand_i[base + 1] = i1; cand_i[base + 2] = i2;
    }
}

// ---------------------------------------------------------------------------
// Kernel C: merge per-block candidates -> global approx top-8 per query.
// ---------------------------------------------------------------------------
__global__ void merge_topk_kernel(const float* __restrict__ cand_s,
                                  const int*   __restrict__ cand_i,
                                  int nblk,
                                  float* __restrict__ topT_s,
                                  int*   __restrict__ topT_i) {
    __shared__ float ls[256 * 8];
    __shared__ int   li[256 * 8];
    const int q = blockIdx.x;
    const int t = threadIdx.x;

    float bs[8]; int bi[8];
#pragma unroll
    for (int j = 0; j < 8; ++j) { bs[j] = -1e30f; bi[j] = -1; }

    for (int blk = t; blk < nblk; blk += 256) {
        const size_t base = ((size_t)blk * B_Q + q) * 3;
#pragma unroll
        for (int j = 0; j < 3; ++j)
            ins8(cand_s[base + j], cand_i[base + j], bs, bi);
    }
#pragma unroll
    for (int j = 0; j < 8; ++j) { ls[t * 8 + j] = bs[j]; li[t * 8 + j] = bi[j]; }
    __syncthreads();

    for (int s = 128; s > 0; s >>= 1) {
        if (t < s) {
#pragma unroll
            for (int j = 0; j < 8; ++j)
                ins8(ls[(t + s) * 8 + j], li[(t + s) * 8 + j], bs, bi);
#pragma unroll
            for (int j = 0; j < 8; ++j) { ls[t * 8 + j] = bs[j]; li[t * 8 + j] = bi[j]; }
        }
        __syncthreads();
    }
    if (t == 0) {
#pragma unroll
        for (int j = 0; j < 8; ++j) { topT_s[q * 8 + j] = bs[j]; topT_i[q * 8 + j] = bi[j]; }
    }
}

// ---------------------------------------------------------------------------
// Kernel D: exact f32 rescore of 8 candidates per query -> top-3 -> out.
// d_out: [0..383] scores f32, [384..767] indices stored as f32 values.
// ---------------------------------------------------------------------------
__global__ void rescore_kernel(const float* __restrict__ corpus,
                               const float* __restrict__ qn,
                               const int*   __restrict__ topT_i,
                               float* __restrict__ out) {
    __shared__ float qrow[DIM];
    __shared__ float sc[8];
    const int q = blockIdx.x;
    const int t = threadIdx.x;
    const int g = t >> 5;       // candidate 0..7
    const int lane = t & 31;

    qrow[t]       = qn[q * DIM + t];
    qrow[t + 256] = qn[q * DIM + t + 256];
    __syncthreads();

    const int r = topT_i[q * 8 + g];
    float d = 0.f, n = 0.f;
    if (r >= 0) {
        const float* row = corpus + (size_t)r * DIM;
        for (int j = lane; j < DIM; j += 32) {
            const float c = row[j];
            d = fmaf(qrow[j], c, d);
            n = fmaf(c, c, n);
        }
    }
#pragma unroll
    for (int m = 16; m > 0; m >>= 1) {
        d += __shfl_xor(d, m);
        n += __shfl_xor(n, m);
    }
    if (lane == 0)
        sc[g] = (r >= 0) ? d / fmaxf(sqrtf(n), 1e-6f) : -1e30f;
    __syncthreads();

    if (t == 0) {
        float b0 = -1e30f, b1 = -1e30f, b2 = -1e30f;
        int   i0 = 0, i1 = 0, i2 = 0;
#pragma unroll
        for (int e = 0; e < 8; ++e)
            ins3(sc[e], topT_i[q * 8 + e], b0, b1, b2, i0, i1, i2);
        out[q * 3 + 0] = b0;
        out[q * 3 + 1] = b1;
        out[q * 3 + 2] = b2;
        out[B_Q * 3 + q * 3 + 0] = (float)i0;
        out[B_Q * 3 + q * 3 + 1] = (float)i1;
        out[B_Q * 3 + q * 3 + 2] = (float)i2;
    }
}

// ---------------------------------------------------------------------------
extern "C" void kernel_launch(void* const* d_in, const int* in_sizes, int n_in,
                              void* d_out, int out_size, void* d_ws, size_t ws_size,
                              hipStream_t stream) {
    const float* qr     = (const float*)d_in[0];  // [128,512]
    const float* corpus = (const float*)d_in[1];  // [500000,512]
    const float* W      = (const float*)d_in[2];  // [512,512]

    float* out = (float*)d_out;
    char*  ws  = (char*)d_ws;

    float*          qn     = (float*)ws;                      // 256 KB
    unsigned short* qfrag  = (unsigned short*)(ws + 262144);  // 128 KB
    float*          topT_s = (float*)(ws + 393216);           // 4 KB
    int*            topT_i = (int*)(ws + 397312);             // 4 KB
    const size_t head = 401408;

    float* cand_s = (float*)(ws + head);                      // 512*128*3 f32
    int*   cand_i = (int*)(ws + head + (size_t)G_SCAN * B_Q * 3 * sizeof(float));

    proj_kernel<<<B_Q, 256, 0, stream>>>(qr, W, qn, qfrag);
    scan_kernel<<<G_SCAN, 512, 0, stream>>>(corpus, qfrag, cand_s, cand_i);
    merge_topk_kernel<<<B_Q, 256, 0, stream>>>(cand_s, cand_i, G_SCAN, topT_s, topT_i);
    rescore_kernel<<<B_Q, 256, 0, stream>>>(corpus, qn, topT_i, out);
}